// Round 10
// baseline (3115.458 us; speedup 1.0000x reference)
//
#include <hip/hip_runtime.h>
#include <hip/hip_bf16.h>

// TSA loss for MI355X.
// loss = mean((outputs-targets)^2) + 0.1 * mean_b( || Pz_b - Px_b ||_F^2 )
// Pipeline: prep (sq/rawT/recon) -> fused dist+select (d2 never materialized;
// per-block 128x2048 stripe with running exact top-26 per row) -> merge
// (4x26 stripe candidates -> global top-26, drop self) -> eigen (Gram trick,
// 8 trace-normalized squarings) -> final reduce.
// d2 arithmetic in the fused kernel is bit-identical to the verified split
// dist kernel (same tile layout, same FMA order), so selection is unchanged.

#define NB 8192
#define ND 64
#define KSEL 26
#define ROUNDS 8
#define NSTR 4      // column stripes (2048 cols each)
#define NTILE 16    // 128-col tiles per stripe

#define FINF 3.0e38f

__device__ __forceinline__ bool lexless(float v, int j, float v2, int j2) {
    return (v < v2) || (v == v2 && j < j2);
}

// ---------------- fused prep: sq | transpose | recon partials --------------
__global__ __launch_bounds__(256) void tsa_prep_kernel(const float* __restrict__ raw,
                                                       const float* __restrict__ outputs,
                                                       const float* __restrict__ targets,
                                                       float* __restrict__ sq,
                                                       float* __restrict__ rawT,
                                                       float* __restrict__ reconP) {
    __shared__ float tile[64][65];
    const int bid = blockIdx.x;
    const int t = threadIdx.x;
    if (bid < 2048) {
        int row = bid * 4 + (t >> 6);
        int lane = t & 63;
        float v = raw[row * 64 + lane];
        float s = v * v;
        #pragma unroll
        for (int off = 1; off < 64; off <<= 1) s += __shfl_xor(s, off);
        if (lane == 0) sq[row] = s;
    } else if (bid < 2176) {
        int r0 = (bid - 2048) * 64;
        #pragma unroll
        for (int r = 0; r < 4; ++r) {
            int e = r * 256 + t;
            int m = e >> 4, c4 = e & 15;
            float4 v = ((const float4*)raw)[(r0 + m) * 16 + c4];
            tile[m][c4 * 4 + 0] = v.x; tile[m][c4 * 4 + 1] = v.y;
            tile[m][c4 * 4 + 2] = v.z; tile[m][c4 * 4 + 3] = v.w;
        }
        __syncthreads();
        #pragma unroll
        for (int r = 0; r < 4; ++r) {
            int e = r * 256 + t;
            int k = e >> 4, c4 = e & 15;
            float4 v;
            v.x = tile[c4 * 4 + 0][k]; v.y = tile[c4 * 4 + 1][k];
            v.z = tile[c4 * 4 + 2][k]; v.w = tile[c4 * 4 + 3][k];
            ((float4*)rawT)[k * 2048 + (r0 >> 2) + c4] = v;
        }
    } else {
        int idx = (bid - 2176) * 256 + t;
        float4 a = ((const float4*)outputs)[idx];
        float4 b = ((const float4*)targets)[idx];
        float dx = a.x - b.x, dy = a.y - b.y, dz = a.z - b.z, dw = a.w - b.w;
        float s = dx * dx + dy * dy + dz * dz + dw * dw;
        #pragma unroll
        for (int off = 1; off < 64; off <<= 1) s += __shfl_xor(s, off);
        __shared__ float ps[4];
        if ((t & 63) == 0) ps[t >> 6] = s;
        __syncthreads();
        if (t == 0) reconP[bid - 2176] = ps[0] + ps[1] + ps[2] + ps[3];
    }
}

// -------- fused distance + stripe-local exact top-26 selection --------------
// Block (sx, by): rows [by*128,+128), cols [sx*2048,+2048). 16 tiles of 128.
// Tile 0: exact 26-round tournament fill per row (16-lane groups).
// Tiles 1..15: threshold test vs running 26th-smallest (lex (val,idx));
// rare exact inserts maintain the set. All selection is intra-wave.
__global__ __launch_bounds__(256) void tsa_distsel_kernel(const float* __restrict__ rawT,
                                                          const float* __restrict__ sq,
                                                          float* __restrict__ candV,
                                                          int* __restrict__ candJ) {
    __shared__ float At[64 * 128];
    __shared__ float Bt[2][64 * 128];
    __shared__ float selV[128][KSEL];
    __shared__ int   selJ[128][KSEL];
    __shared__ float rowMaxV[128];
    __shared__ int   rowMaxJ[128];
    __shared__ int   rowMaxS[128];

    const int t = threadIdx.x;
    const int sx = blockIdx.x;
    const int m0 = blockIdx.y * 128;
    const int c0 = sx * 2048;
    const float4* rT4 = (const float4*)rawT;
    float4* At4 = (float4*)At;

    #pragma unroll
    for (int r = 0; r < 8; ++r) {
        int e = r * 256 + t;
        int k = e >> 5, c = e & 31;
        At4[e] = rT4[k * 2048 + (m0 >> 2) + c];
        ((float4*)Bt[0])[e] = rT4[k * 2048 + (c0 >> 2) + c];
    }
    __syncthreads();

    const int tx = t >> 4;       // row group: rows tx*8..+8
    const int ty = t & 15;       // col lane within group
    const int grp = (t & 63) >> 4;  // group index within wave
    float sqm[8];
    #pragma unroll
    for (int i = 0; i < 8; ++i) sqm[i] = sq[m0 + tx * 8 + i];

    #pragma unroll 1
    for (int tile = 0; tile < NTILE; ++tile) {
        const int cur = tile & 1;
        const int n0 = c0 + tile * 128;
        // prefetch next tile into regs (hidden under GEMM)
        float4 pre[8];
        if (tile + 1 < NTILE) {
            int nn0 = n0 + 128;
            #pragma unroll
            for (int r = 0; r < 8; ++r) {
                int e = r * 256 + t;
                int k = e >> 5, c = e & 31;
                pre[r] = rT4[k * 2048 + (nn0 >> 2) + c];
            }
        }
        // GEMM 128x128 tile (identical arithmetic to the split dist kernel)
        float acc[8][8];
        #pragma unroll
        for (int i = 0; i < 8; ++i)
            #pragma unroll
            for (int j = 0; j < 8; ++j) acc[i][j] = 0.0f;
        const float4* B4 = (const float4*)Bt[cur];
        #pragma unroll 4
        for (int k = 0; k < 64; ++k) {
            float4 a0 = At4[k * 32 + tx * 2 + 0];
            float4 a1 = At4[k * 32 + tx * 2 + 1];
            float4 b0 = B4[k * 32 + ty];
            float4 b1 = B4[k * 32 + 16 + ty];
            float av[8] = {a0.x, a0.y, a0.z, a0.w, a1.x, a1.y, a1.z, a1.w};
            float bw[8] = {b0.x, b0.y, b0.z, b0.w, b1.x, b1.y, b1.z, b1.w};
            #pragma unroll
            for (int i = 0; i < 8; ++i)
                #pragma unroll
                for (int j = 0; j < 8; ++j)
                    acc[i][j] += av[i] * bw[j];
        }
        float sqn[8];
        #pragma unroll
        for (int j = 0; j < 4; ++j) {
            sqn[j]     = sq[n0 + ty * 4 + j];
            sqn[4 + j] = sq[n0 + 64 + ty * 4 + j];
        }

        if (tile == 0) {
            // ---- exact top-26 fill per row ----
            #pragma unroll 1
            for (int i = 0; i < 8; ++i) {
                const int r = tx * 8 + i;
                float v[8]; int jx[8];
                #pragma unroll
                for (int j = 0; j < 8; ++j) {
                    v[j] = sqm[i] + sqn[j] - 2.0f * acc[i][j];
                    jx[j] = n0 + ((j < 4) ? (ty * 4 + j) : (64 + ty * 4 + j - 4));
                }
                unsigned rem = 0;
                #pragma unroll 1
                for (int round = 0; round < KSEL; ++round) {
                    float bv = FINF; int bj = 0x7fffffff; int bq = -1;
                    #pragma unroll
                    for (int q = 0; q < 8; ++q) {
                        bool ok = ((rem >> q) & 1u) == 0u;
                        if (ok && lexless(v[q], jx[q], bv, bj)) { bv = v[q]; bj = jx[q]; bq = q; }
                    }
                    float obv = bv; int obj = bj;
                    #pragma unroll
                    for (int off = 1; off < 16; off <<= 1) {
                        float rv = __shfl_xor(bv, off);
                        int rj = __shfl_xor(bj, off);
                        if (lexless(rv, rj, bv, bj)) { bv = rv; bj = rj; }
                    }
                    if (bq >= 0 && obv == bv && obj == bj) rem |= 1u << bq;  // unique idx
                    if (ty == 0) { selV[r][round] = bv; selJ[r][round] = bj; }
                }
                if (ty == 0) {
                    float mv = selV[r][0]; int mj = selJ[r][0]; int ms = 0;
                    #pragma unroll 1
                    for (int s = 1; s < KSEL; ++s) {
                        float sv = selV[r][s]; int sj = selJ[r][s];
                        if (sv > mv || (sv == mv && sj > mj)) { mv = sv; mj = sj; ms = s; }
                    }
                    rowMaxV[r] = mv; rowMaxJ[r] = mj; rowMaxS[r] = ms;
                }
            }
            asm volatile("s_waitcnt lgkmcnt(0)" ::: "memory");
        } else {
            // ---- threshold + rare exact insert ----
            #pragma unroll 1
            for (int i = 0; i < 8; ++i) {
                const int r = tx * 8 + i;
                float Tv = rowMaxV[r]; int Tj = rowMaxJ[r];
                float v[8]; int jx[8];
                bool any = false;
                #pragma unroll
                for (int j = 0; j < 8; ++j) {
                    v[j] = sqm[i] + sqn[j] - 2.0f * acc[i][j];
                    jx[j] = n0 + ((j < 4) ? (ty * 4 + j) : (64 + ty * 4 + j - 4));
                    any = any || lexless(v[j], jx[j], Tv, Tj);
                }
                unsigned long long bal = __ballot(any);
                if (((bal >> (grp * 16)) & 0xFFFFull) == 0ull) continue;
                unsigned rem = 0;
                while (true) {
                    float bv = FINF; int bj = 0x7fffffff; int bq = -1;
                    #pragma unroll
                    for (int q = 0; q < 8; ++q) {
                        bool ok = ((rem >> q) & 1u) == 0u;
                        if (ok && lexless(v[q], jx[q], bv, bj)) { bv = v[q]; bj = jx[q]; bq = q; }
                    }
                    float obv = bv; int obj = bj;
                    #pragma unroll
                    for (int off = 1; off < 16; off <<= 1) {
                        float rv = __shfl_xor(bv, off);
                        int rj = __shfl_xor(bj, off);
                        if (lexless(rv, rj, bv, bj)) { bv = rv; bj = rj; }
                    }
                    if (!lexless(bv, bj, Tv, Tj)) break;
                    if (bq >= 0 && obv == bv && obj == bj) rem |= 1u << bq;
                    if (ty == 0) {
                        int ms = rowMaxS[r];
                        selV[r][ms] = bv; selJ[r][ms] = bj;
                        float mv = selV[r][0]; int mj = selJ[r][0]; int m2 = 0;
                        #pragma unroll 1
                        for (int s = 1; s < KSEL; ++s) {
                            float sv = selV[r][s]; int sj = selJ[r][s];
                            if (sv > mv || (sv == mv && sj > mj)) { mv = sv; mj = sj; m2 = s; }
                        }
                        rowMaxV[r] = mv; rowMaxJ[r] = mj; rowMaxS[r] = m2;
                    }
                    asm volatile("s_waitcnt lgkmcnt(0)" ::: "memory");
                    Tv = rowMaxV[r]; Tj = rowMaxJ[r];
                }
            }
        }
        // write prefetched tile into the other buffer; one barrier per tile
        if (tile + 1 < NTILE) {
            float4* Bn = (float4*)Bt[cur ^ 1];
            #pragma unroll
            for (int r = 0; r < 8; ++r) Bn[r * 256 + t] = pre[r];
        }
        __syncthreads();
    }

    // write stripe candidates: cand[row][sx][slot]
    for (int w = t; w < 128 * KSEL; w += 256) {
        int r = w / KSEL, s = w % KSEL;
        int row = m0 + r;
        candV[(row * NSTR + sx) * KSEL + s] = selV[r][s];
        candJ[(row * NSTR + sx) * KSEL + s] = selJ[r][s];
    }
}

// ---------------- merge: 104 stripe candidates -> 25 neighbors --------------
__global__ __launch_bounds__(256) void tsa_merge_kernel(const float* __restrict__ candV,
                                                        const int* __restrict__ candJ,
                                                        int* __restrict__ nbrs) {
    const int t = threadIdx.x, lane = t & 63, wv = t >> 6;
    const int row = blockIdx.x * 4 + wv;
    const float* cv = candV + row * (NSTR * KSEL);
    const int* cj = candJ + row * (NSTR * KSEL);
    float v0 = cv[lane]; int j0 = cj[lane];
    bool has1 = lane < (NSTR * KSEL - 64);
    float v1 = has1 ? cv[64 + lane] : FINF;
    int   j1 = has1 ? cj[64 + lane] : 0x7ffffffe;
    unsigned rm = 0;
    for (int round = 0; round < KSEL; ++round) {
        float bv = FINF; int bj = 0x7fffffff;
        if (!(rm & 1u)) { bv = v0; bj = j0; }
        if (!(rm & 2u) && lexless(v1, j1, bv, bj)) { bv = v1; bj = j1; }
        #pragma unroll
        for (int off = 1; off < 64; off <<= 1) {
            float rv = __shfl_xor(bv, off);
            int rj = __shfl_xor(bj, off);
            if (lexless(rv, rj, bv, bj)) { bv = rv; bj = rj; }
        }
        if (bv == v0 && bj == j0) rm |= 1u;
        else if (bv == v1 && bj == j1) rm |= 2u;
        if (lane == 0 && round > 0) nbrs[row * 25 + round - 1] = bj;
    }
}

// ---------------- per-sample eigen + per_sample value -----------------------
// (unchanged from round 9: barrier-free, gt aliases zx, 54,272 B LDS)
__global__ __launch_bounds__(256) void tsa_eigen_kernel(const int* __restrict__ nbrs,
                                                        const float* __restrict__ latent,
                                                        const float* __restrict__ raw,
                                                        float* __restrict__ tsaV) {
    __shared__ __align__(16) float pool[8][1696];
    const int t = threadIdx.x, lane = t & 63, wv = t >> 6;
    const int i = blockIdx.x * 4 + wv;
    const int half = lane >> 5;
    const int b = lane & 31;
    const bool act = b < 25;
    const int bb = act ? b : 0;
    const float* src = half ? raw : latent;
    float* slice = pool[wv * 2 + half];

    int nb = 0;
    if (act) {
        nb = nbrs[i * 25 + b];
        const float4* s4 = (const float4*)(src + nb * 64);
        float4* dst = (float4*)(slice + b * 68);
        #pragma unroll
        for (int c = 0; c < 16; ++c) dst[c] = s4[c];
    }
    asm volatile("s_waitcnt lgkmcnt(0)" ::: "memory");

    float g[25];
    #pragma unroll
    for (int a = 0; a < 25; ++a) g[a] = 0.0f;
    #pragma unroll 1
    for (int ch = 0; ch < 4; ++ch) {
        float ow[16];
        const float4* op = (const float4*)(slice + bb * 68);
        ((float4*)ow)[0] = op[ch * 4 + 0];
        ((float4*)ow)[1] = op[ch * 4 + 1];
        ((float4*)ow)[2] = op[ch * 4 + 2];
        ((float4*)ow)[3] = op[ch * 4 + 3];
        #pragma unroll
        for (int a = 0; a < 25; ++a) {
            float rr[16];
            const float4* rp = (const float4*)(slice + a * 68);
            ((float4*)rr)[0] = rp[ch * 4 + 0];
            ((float4*)rr)[1] = rp[ch * 4 + 1];
            ((float4*)rr)[2] = rp[ch * 4 + 2];
            ((float4*)rr)[3] = rp[ch * 4 + 3];
            float s = 0.0f;
            #pragma unroll
            for (int d4 = 0; d4 < 16; ++d4) s += ow[d4] * rr[d4];
            g[a] += s;
        }
    }

    {
        float rs_own = 0.0f;
        #pragma unroll
        for (int a = 0; a < 25; ++a) rs_own += g[a];
        float grand = 0.0f;
        float rsA[25];
        #pragma unroll
        for (int a = 0; a < 25; ++a) {
            rsA[a] = __shfl(rs_own, half * 32 + a);
            grand += rsA[a];
        }
        const float c1 = 1.0f / 25.0f, c2 = 1.0f / 625.0f;
        #pragma unroll
        for (int a = 0; a < 25; ++a)
            g[a] = g[a] - rsA[a] * c1 - rs_own * c1 + grand * c2;
    }

    #pragma unroll 1
    for (int rd = 0; rd < ROUNDS; ++rd) {
        float ss = 0.0f;
        #pragma unroll
        for (int r2 = 0; r2 < 25; ++r2) ss += g[r2] * g[r2];
        ss = act ? ss : 0.0f;
        #pragma unroll
        for (int off = 1; off < 32; off <<= 1) ss += __shfl_xor(ss, off);
        float inv = 1.0f / ss;
        if (act) {
            float4* gw = (float4*)(slice + b * 28);
            gw[0] = make_float4(g[0], g[1], g[2], g[3]);
            gw[1] = make_float4(g[4], g[5], g[6], g[7]);
            gw[2] = make_float4(g[8], g[9], g[10], g[11]);
            gw[3] = make_float4(g[12], g[13], g[14], g[15]);
            gw[4] = make_float4(g[16], g[17], g[18], g[19]);
            gw[5] = make_float4(g[20], g[21], g[22], g[23]);
            gw[6] = make_float4(g[24], 0.0f, 0.0f, 0.0f);
        }
        asm volatile("s_waitcnt lgkmcnt(0)" ::: "memory");
        float ng[25];
        #pragma unroll
        for (int r2 = 0; r2 < 25; ++r2) ng[r2] = 0.0f;
        #pragma unroll
        for (int c = 0; c < 25; ++c) {
            float cc2[28];
            const float4* gr = (const float4*)(slice + c * 28);
            ((float4*)cc2)[0] = gr[0];
            ((float4*)cc2)[1] = gr[1];
            ((float4*)cc2)[2] = gr[2];
            ((float4*)cc2)[3] = gr[3];
            ((float4*)cc2)[4] = gr[4];
            ((float4*)cc2)[5] = gr[5];
            ((float4*)cc2)[6] = gr[6];
            float m2 = g[c];
            #pragma unroll
            for (int r2 = 0; r2 < 25; ++r2) ng[r2] += cc2[r2] * m2;
        }
        #pragma unroll
        for (int r2 = 0; r2 < 25; ++r2) g[r2] = ng[r2] * inv;
    }

    if (act) {
        float4* gw = (float4*)(slice + b * 28);
        gw[0] = make_float4(g[0], g[1], g[2], g[3]);
        gw[1] = make_float4(g[4], g[5], g[6], g[7]);
        gw[2] = make_float4(g[8], g[9], g[10], g[11]);
        gw[3] = make_float4(g[12], g[13], g[14], g[15]);
        gw[4] = make_float4(g[16], g[17], g[18], g[19]);
        gw[5] = make_float4(g[20], g[21], g[22], g[23]);
        gw[6] = make_float4(g[24], 0.0f, 0.0f, 0.0f);
    }
    asm volatile("s_waitcnt lgkmcnt(0)" ::: "memory");

    float dv = act ? slice[b * 28 + b] : -1.0f;
    int bi = b;
    #pragma unroll
    for (int off = 1; off < 32; off <<= 1) {
        float ov = __shfl_xor(dv, off);
        int oi = __shfl_xor(bi, off);
        bool take = (ov > dv) || (ov == dv && oi < bi);
        dv = take ? ov : dv;
        bi = take ? oi : bi;
    }
    int jz = __shfl(bi, 0);
    int jxm = __shfl(bi, 32);

    const float* slice0 = pool[wv * 2 + 0];
    const float* slice1 = pool[wv * 2 + 1];
    float wzArr[28], wxArr[28];
    {
        const float4* wz4 = (const float4*)(slice0 + jz * 28);
        const float4* wx4 = (const float4*)(slice1 + jxm * 28);
        #pragma unroll
        for (int q = 0; q < 7; ++q) {
            ((float4*)wzArr)[q] = wz4[q];
            ((float4*)wxArr)[q] = wx4[q];
        }
    }
    float szs = 0.0f, sxs = 0.0f;
    #pragma unroll
    for (int k = 0; k < 25; ++k) { szs += wzArr[k]; sxs += wxArr[k]; }
    float azc = szs * (1.0f / 25.0f), axc = sxs * (1.0f / 25.0f);

    float uz = 0.0f, ux = 0.0f;
    #pragma unroll
    for (int k = 0; k < 25; ++k) {
        int nbz = __shfl(nb, k);
        int nbx = __shfl(nb, 32 + k);
        uz += latent[nbz * 64 + lane] * (wzArr[k] - azc);
        ux += raw[nbx * 64 + lane] * (wxArr[k] - axc);
    }
    float aa = uz * uz, bbv = ux * ux, ccv = uz * ux;
    #pragma unroll
    for (int off = 1; off < 64; off <<= 1) {
        aa += __shfl_xor(aa, off);
        bbv += __shfl_xor(bbv, off);
        ccv += __shfl_xor(ccv, off);
    }
    if (lane == 0) {
        float dot2 = (ccv * ccv) / fmaxf(aa * bbv, 1e-30f);
        tsaV[i] = 2.0f - 2.0f * dot2;
    }
}

// ---------------- final: out = sum(reconP)/524288 + 0.1*mean(tsaV) ----------
__global__ __launch_bounds__(256) void tsa_final_kernel(const float* __restrict__ tsaV,
                                                        const float* __restrict__ reconP,
                                                        float* __restrict__ out) {
    const int t = threadIdx.x;
    float s = 0.0f;
    const float4* v4 = (const float4*)tsaV;
    for (int e = t; e < 2048; e += 256) {
        float4 v = v4[e];
        s += (v.x + v.y) + (v.z + v.w);
    }
    float r = 0.0f;
    if (t < 128) {
        float4 p = ((const float4*)reconP)[t];
        r = (p.x + p.y) + (p.z + p.w);
    }
    #pragma unroll
    for (int off = 1; off < 64; off <<= 1) {
        s += __shfl_xor(s, off);
        r += __shfl_xor(r, off);
    }
    __shared__ float ps[4], pr[4];
    if ((t & 63) == 0) { ps[t >> 6] = s; pr[t >> 6] = r; }
    __syncthreads();
    if (t == 0) {
        float tot = ps[0] + ps[1] + ps[2] + ps[3];
        float rec = pr[0] + pr[1] + pr[2] + pr[3];
        out[0] = rec * (1.0f / 524288.0f) + 0.1f * (tot * (1.0f / 8192.0f));
    }
}

extern "C" void kernel_launch(void* const* d_in, const int* in_sizes, int n_in,
                              void* d_out, int out_size, void* d_ws, size_t ws_size,
                              hipStream_t stream) {
    const float* outputs = (const float*)d_in[0];
    const float* targets = (const float*)d_in[1];
    const float* latent  = (const float*)d_in[2];
    const float* raw     = (const float*)d_in[3];

    float* ws = (float*)d_ws;
    // ws layout (floats):
    float* sq     = ws;                       // 8192
    float* rawT   = ws + 8192;                // 524288
    int*   nbrs   = (int*)(ws + 532480);      // 8192*25 -> ends 737280
    float* reconP = ws + 737280;              // 512
    float* tsaV   = ws + 737792;              // 8192 -> ends 745984
    float* candV  = ws + 745984;              // 8192*104 = 851968
    int*   candJ  = (int*)(ws + 1597952);     // 851968 -> ends 2449920 (~9.8 MB)

    tsa_prep_kernel<<<2688, 256, 0, stream>>>(raw, outputs, targets, sq, rawT, reconP);
    {
        dim3 g(NSTR, 64);
        tsa_distsel_kernel<<<g, 256, 0, stream>>>(rawT, sq, candV, candJ);
    }
    tsa_merge_kernel<<<2048, 256, 0, stream>>>(candV, candJ, nbrs);
    tsa_eigen_kernel<<<2048, 256, 0, stream>>>(nbrs, latent, raw, tsaV);
    tsa_final_kernel<<<1, 256, 0, stream>>>(tsaV, reconP, (float*)d_out);
}

// Round 11
// 703.022 us; speedup vs baseline: 4.4315x; 4.4315x over previous
//
#include <hip/hip_runtime.h>
#include <hip/hip_bf16.h>

// TSA loss for MI355X.
// loss = mean((outputs-targets)^2) + 0.1 * mean_b( || Pz_b - Px_b ||_F^2 )
// Pipeline: prep -> dist0+sel0 (exact top-26 of cols [0,2048) per row; slot 25
// is the lex threshold) -> filter (cols [2048,8192): recompute d2 with
// bit-identical GEMM, keep values lex-below threshold; ~78 survivors/row)
// -> merge (top-26 of 26+survivors, drop self) -> eigen -> final.
// No running top-k anywhere (round-10 lesson: inserts are NOT rare, 72/row).

#define NB 8192
#define ND 64
#define KSEL 26
#define ROUNDS 8
#define W0 2048     // chunk0 columns (threshold source)
#define NCH 12      // filter column chunks of 512
#define CCAP 32     // survivor capacity per (row, chunk); mean 6.5

#define FINF 3.0e38f

__device__ __forceinline__ bool lexless(float v, int j, float v2, int j2) {
    return (v < v2) || (v == v2 && j < j2);
}

// ---------------- fused prep: sq | transpose | recon partials --------------
__global__ __launch_bounds__(256) void tsa_prep_kernel(const float* __restrict__ raw,
                                                       const float* __restrict__ outputs,
                                                       const float* __restrict__ targets,
                                                       float* __restrict__ sq,
                                                       float* __restrict__ rawT,
                                                       float* __restrict__ reconP) {
    __shared__ float tile[64][65];
    const int bid = blockIdx.x;
    const int t = threadIdx.x;
    if (bid < 2048) {
        int row = bid * 4 + (t >> 6);
        int lane = t & 63;
        float v = raw[row * 64 + lane];
        float s = v * v;
        #pragma unroll
        for (int off = 1; off < 64; off <<= 1) s += __shfl_xor(s, off);
        if (lane == 0) sq[row] = s;
    } else if (bid < 2176) {
        int r0 = (bid - 2048) * 64;
        #pragma unroll
        for (int r = 0; r < 4; ++r) {
            int e = r * 256 + t;
            int m = e >> 4, c4 = e & 15;
            float4 v = ((const float4*)raw)[(r0 + m) * 16 + c4];
            tile[m][c4 * 4 + 0] = v.x; tile[m][c4 * 4 + 1] = v.y;
            tile[m][c4 * 4 + 2] = v.z; tile[m][c4 * 4 + 3] = v.w;
        }
        __syncthreads();
        #pragma unroll
        for (int r = 0; r < 4; ++r) {
            int e = r * 256 + t;
            int k = e >> 4, c4 = e & 15;
            float4 v;
            v.x = tile[c4 * 4 + 0][k]; v.y = tile[c4 * 4 + 1][k];
            v.z = tile[c4 * 4 + 2][k]; v.w = tile[c4 * 4 + 3][k];
            ((float4*)rawT)[k * 2048 + (r0 >> 2) + c4] = v;
        }
    } else {
        int idx = (bid - 2176) * 256 + t;
        float4 a = ((const float4*)outputs)[idx];
        float4 b = ((const float4*)targets)[idx];
        float dx = a.x - b.x, dy = a.y - b.y, dz = a.z - b.z, dw = a.w - b.w;
        float s = dx * dx + dy * dy + dz * dz + dw * dw;
        #pragma unroll
        for (int off = 1; off < 64; off <<= 1) s += __shfl_xor(s, off);
        __shared__ float ps[4];
        if ((t & 63) == 0) ps[t >> 6] = s;
        __syncthreads();
        if (t == 0) reconP[bid - 2176] = ps[0] + ps[1] + ps[2] + ps[3];
    }
}

// ---------------- dist0: d2_0[row][0..2048) = distances to chunk0 cols ------
// Verified 128x128 tile GEMM; only the output stride changed (8192 -> 2048).
__global__ __launch_bounds__(256) void tsa_dist0_kernel(const float* __restrict__ rawT,
                                                        const float* __restrict__ sq,
                                                        float* __restrict__ d2,
                                                        int rowBase) {
    __shared__ float At[64 * 128];
    __shared__ float Bt[64 * 128];
    const int t = threadIdx.x;
    const int m0 = rowBase + blockIdx.y * 128;
    const int n0 = blockIdx.x * 128;          // 0..15 * 128 < 2048
    const float4* rT4 = (const float4*)rawT;
    float4* At4 = (float4*)At;
    float4* Bt4 = (float4*)Bt;
    #pragma unroll
    for (int r = 0; r < 8; ++r) {
        int e = r * 256 + t;
        int k = e >> 5, c = e & 31;
        At4[e] = rT4[k * 2048 + (m0 >> 2) + c];
        Bt4[e] = rT4[k * 2048 + (n0 >> 2) + c];
    }
    __syncthreads();
    const int tx = t >> 4;
    const int ty = t & 15;
    float acc[8][8];
    #pragma unroll
    for (int i = 0; i < 8; ++i)
        #pragma unroll
        for (int j = 0; j < 8; ++j) acc[i][j] = 0.0f;

    #pragma unroll 4
    for (int k = 0; k < 64; ++k) {
        float4 a0 = At4[k * 32 + tx * 2 + 0];
        float4 a1 = At4[k * 32 + tx * 2 + 1];
        float4 b0 = Bt4[k * 32 + ty];
        float4 b1 = Bt4[k * 32 + 16 + ty];
        float av[8] = {a0.x, a0.y, a0.z, a0.w, a1.x, a1.y, a1.z, a1.w};
        float bw[8] = {b0.x, b0.y, b0.z, b0.w, b1.x, b1.y, b1.z, b1.w};
        #pragma unroll
        for (int i = 0; i < 8; ++i)
            #pragma unroll
            for (int j = 0; j < 8; ++j)
                acc[i][j] += av[i] * bw[j];
    }
    float sqm[8], sqn[8];
    #pragma unroll
    for (int i = 0; i < 8; ++i) sqm[i] = sq[m0 + tx * 8 + i];
    #pragma unroll
    for (int j = 0; j < 4; ++j) {
        sqn[j]     = sq[n0 + ty * 4 + j];
        sqn[4 + j] = sq[n0 + 64 + ty * 4 + j];
    }
    #pragma unroll
    for (int i = 0; i < 8; ++i) {
        size_t rowoff = (size_t)(m0 - rowBase + tx * 8 + i) * W0;
        float4 w0, w1;
        w0.x = sqm[i] + sqn[0] - 2.0f * acc[i][0];
        w0.y = sqm[i] + sqn[1] - 2.0f * acc[i][1];
        w0.z = sqm[i] + sqn[2] - 2.0f * acc[i][2];
        w0.w = sqm[i] + sqn[3] - 2.0f * acc[i][3];
        w1.x = sqm[i] + sqn[4] - 2.0f * acc[i][4];
        w1.y = sqm[i] + sqn[5] - 2.0f * acc[i][5];
        w1.z = sqm[i] + sqn[6] - 2.0f * acc[i][6];
        w1.w = sqm[i] + sqn[7] - 2.0f * acc[i][7];
        float4* wp = (float4*)(d2 + rowoff + n0);
        wp[ty] = w0;
        wp[16 + ty] = w1;
    }
}

// ---------------- sel0: exact top-26 of chunk0 per row (1 wave/row) ---------
// Verified tournament (old select phase-1); slot 25 = lex threshold.
__global__ __launch_bounds__(256) void tsa_sel0_kernel(const float* __restrict__ d2,
                                                       float* __restrict__ sel26V,
                                                       int* __restrict__ sel26J,
                                                       int rowBase) {
    const int t = threadIdx.x;
    const int lane = t & 63;
    const int wv = t >> 6;
    const int lrow = blockIdx.x * 4 + wv;
    const int i = rowBase + lrow;
    const float4* row4 = (const float4*)(d2 + (size_t)lrow * W0);

    float v[32];
    #pragma unroll
    for (int r = 0; r < 8; ++r) {
        float4 f = row4[r * 64 + lane];
        v[4 * r + 0] = f.x; v[4 * r + 1] = f.y;
        v[4 * r + 2] = f.z; v[4 * r + 3] = f.w;
    }
    unsigned removed = 0;
    for (int round = 0; round < KSEL; ++round) {
        float bv = FINF; int bq = 0;
        #pragma unroll
        for (int q = 0; q < 32; ++q) {
            bool ok = ((removed >> q) & 1u) == 0u;
            bool c = ok && (v[q] < bv);
            bv = c ? v[q] : bv;
            bq = c ? q : bq;
        }
        int bj = (bq >> 2) * 256 + lane * 4 + (bq & 3);
        #pragma unroll
        for (int off = 1; off < 64; off <<= 1) {
            float rv = __shfl_xor(bv, off);
            int rj = __shfl_xor(bj, off);
            bool take = (rv < bv) || (rv == bv && rj < bj);
            bv = take ? rv : bv;
            bj = take ? rj : bj;
        }
        int ol = (bj >> 2) & 63;
        int oq = ((bj >> 8) << 2) | (bj & 3);
        if (lane == ol) removed |= (1u << oq);
        if (lane == 0) { sel26V[i * KSEL + round] = bv; sel26J[i * KSEL + round] = bj; }
    }
}

// ---------------- filter: cols [2048,8192), keep values lex-below T ---------
// Block (ch, by): rows [by*128,+128), cols [2048+ch*512,+512) = 4 tiles.
// Survivors compacted via ballot into per-(row,chunk) sub-buffers; counters
// live in registers (uniform within each 16-lane row-group). No LDS RMW.
__global__ __launch_bounds__(256) void tsa_filter_kernel(const float* __restrict__ rawT,
                                                         const float* __restrict__ sq,
                                                         const float* __restrict__ sel26V,
                                                         const int* __restrict__ sel26J,
                                                         float* __restrict__ survV,
                                                         int* __restrict__ survJ,
                                                         int* __restrict__ cnt) {
    __shared__ float At[64 * 128];
    __shared__ float Bt[64 * 128];
    const int t = threadIdx.x;
    const int ch = blockIdx.x;
    const int m0 = blockIdx.y * 128;
    const int c0 = W0 + ch * 512;
    const float4* rT4 = (const float4*)rawT;
    float4* At4 = (float4*)At;
    float4* Bt4 = (float4*)Bt;

    #pragma unroll
    for (int r = 0; r < 8; ++r) {
        int e = r * 256 + t;
        int k = e >> 5, c = e & 31;
        At4[e] = rT4[k * 2048 + (m0 >> 2) + c];
        Bt4[e] = rT4[k * 2048 + (c0 >> 2) + c];
    }
    __syncthreads();

    const int tx = t >> 4;
    const int ty = t & 15;
    const int grp = (t & 63) >> 4;
    float sqm[8], Tv[8]; int Tj[8]; int cntr[8];
    #pragma unroll
    for (int i = 0; i < 8; ++i) {
        int row = m0 + tx * 8 + i;
        sqm[i] = sq[row];
        Tv[i] = sel26V[row * KSEL + 25];
        Tj[i] = sel26J[row * KSEL + 25];
        cntr[i] = 0;
    }

    #pragma unroll 1
    for (int tile = 0; tile < 4; ++tile) {
        const int n0 = c0 + tile * 128;
        float4 pre[8];
        if (tile < 3) {
            int nn0 = n0 + 128;
            #pragma unroll
            for (int r = 0; r < 8; ++r) {
                int e = r * 256 + t;
                int k = e >> 5, c = e & 31;
                pre[r] = rT4[k * 2048 + (nn0 >> 2) + c];
            }
        }
        float acc[8][8];
        #pragma unroll
        for (int i = 0; i < 8; ++i)
            #pragma unroll
            for (int j = 0; j < 8; ++j) acc[i][j] = 0.0f;
        #pragma unroll 4
        for (int k = 0; k < 64; ++k) {
            float4 a0 = At4[k * 32 + tx * 2 + 0];
            float4 a1 = At4[k * 32 + tx * 2 + 1];
            float4 b0 = Bt4[k * 32 + ty];
            float4 b1 = Bt4[k * 32 + 16 + ty];
            float av[8] = {a0.x, a0.y, a0.z, a0.w, a1.x, a1.y, a1.z, a1.w};
            float bw[8] = {b0.x, b0.y, b0.z, b0.w, b1.x, b1.y, b1.z, b1.w};
            #pragma unroll
            for (int i = 0; i < 8; ++i)
                #pragma unroll
                for (int j = 0; j < 8; ++j)
                    acc[i][j] += av[i] * bw[j];
        }
        float sqn[8];
        #pragma unroll
        for (int j = 0; j < 4; ++j) {
            sqn[j]     = sq[n0 + ty * 4 + j];
            sqn[4 + j] = sq[n0 + 64 + ty * 4 + j];
        }
        #pragma unroll 1
        for (int i = 0; i < 8; ++i) {
            const int row = m0 + tx * 8 + i;
            float v[8]; int jx[8];
            bool any = false;
            #pragma unroll
            for (int j = 0; j < 8; ++j) {
                v[j] = sqm[i] + sqn[j] - 2.0f * acc[i][j];
                jx[j] = n0 + ((j < 4) ? (ty * 4 + j) : (64 + ty * 4 + j - 4));
                any = any || lexless(v[j], jx[j], Tv[i], Tj[i]);
            }
            unsigned long long bal = __ballot(any);
            unsigned m16 = (unsigned)((bal >> (grp * 16)) & 0xFFFFull);
            if (m16) {
                int base = cntr[i];
                #pragma unroll 1
                for (int j = 0; j < 8; ++j) {
                    bool p = lexless(v[j], jx[j], Tv[i], Tj[i]);
                    unsigned long long bj2 = __ballot(p);
                    unsigned pm = (unsigned)((bj2 >> (grp * 16)) & 0xFFFFull);
                    if (p) {
                        int off = base + __popc(pm & ((1u << ty) - 1u));
                        if (off < CCAP) {
                            int sidx = (row * NCH + ch) * CCAP + off;
                            survV[sidx] = v[j];
                            survJ[sidx] = jx[j];
                        }
                    }
                    base += __popc(pm);
                }
                cntr[i] = base;
            }
        }
        if (tile < 3) {
            __syncthreads();
            #pragma unroll
            for (int r = 0; r < 8; ++r) Bt4[r * 256 + t] = pre[r];
            __syncthreads();
        }
    }
    if (ty == 0) {
        #pragma unroll
        for (int i = 0; i < 8; ++i) {
            int row = m0 + tx * 8 + i;
            cnt[row * NCH + ch] = (cntr[i] < CCAP) ? cntr[i] : CCAP;
        }
    }
}

// ---------------- merge: top-26 of {chunk0 26} U survivors; drop self -------
__global__ __launch_bounds__(256) void tsa_merge_kernel(const float* __restrict__ sel26V,
                                                        const int* __restrict__ sel26J,
                                                        const float* __restrict__ survV,
                                                        const int* __restrict__ survJ,
                                                        const int* __restrict__ cnt,
                                                        int* __restrict__ nbrs) {
    const int t = threadIdx.x, lane = t & 63, wv = t >> 6;
    const int row = blockIdx.x * 4 + wv;
    int pfx[NCH + 1];
    pfx[0] = KSEL;
    #pragma unroll
    for (int c = 0; c < NCH; ++c) {
        int cc = cnt[row * NCH + c];
        cc = (cc < CCAP) ? cc : CCAP;
        pfx[c + 1] = pfx[c] + cc;
    }
    const int total = pfx[NCH];
    float m[7]; int mj[7];
    #pragma unroll 1
    for (int s = 0; s < 7; ++s) {
        int e = lane + s * 64;
        float val = FINF; int jj = 0x7f000000 + e;
        if (e < KSEL) {
            val = sel26V[row * KSEL + e];
            jj = sel26J[row * KSEL + e];
        } else if (e < total) {
            int c = 0;
            #pragma unroll
            for (int q = 0; q < NCH; ++q)
                if (e >= pfx[q + 1]) c = q + 1;
            int off = e - pfx[c];
            val = survV[(row * NCH + c) * CCAP + off];
            jj = survJ[(row * NCH + c) * CCAP + off];
        }
        m[s] = val; mj[s] = jj;
    }
    unsigned rem = 0;
    for (int round = 0; round < KSEL; ++round) {
        float bv = FINF; int bj = 0x7fffffff; int bq = -1;
        #pragma unroll
        for (int s = 0; s < 7; ++s) {
            bool ok = ((rem >> s) & 1u) == 0u;
            if (ok && lexless(m[s], mj[s], bv, bj)) { bv = m[s]; bj = mj[s]; bq = s; }
        }
        float obv = bv; int obj = bj;
        #pragma unroll
        for (int off = 1; off < 64; off <<= 1) {
            float rv = __shfl_xor(bv, off);
            int rj = __shfl_xor(bj, off);
            if (lexless(rv, rj, bv, bj)) { bv = rv; bj = rj; }
        }
        if (bq >= 0 && obv == bv && obj == bj) rem |= 1u << bq;
        if (lane == 0 && round > 0) nbrs[row * 25 + round - 1] = bj;
    }
}

// ---------------- per-sample eigen + per_sample value (verified, unchanged) -
__global__ __launch_bounds__(256) void tsa_eigen_kernel(const int* __restrict__ nbrs,
                                                        const float* __restrict__ latent,
                                                        const float* __restrict__ raw,
                                                        float* __restrict__ tsaV) {
    __shared__ __align__(16) float pool[8][1696];
    const int t = threadIdx.x, lane = t & 63, wv = t >> 6;
    const int i = blockIdx.x * 4 + wv;
    const int half = lane >> 5;
    const int b = lane & 31;
    const bool act = b < 25;
    const int bb = act ? b : 0;
    const float* src = half ? raw : latent;
    float* slice = pool[wv * 2 + half];

    int nb = 0;
    if (act) {
        nb = nbrs[i * 25 + b];
        const float4* s4 = (const float4*)(src + nb * 64);
        float4* dst = (float4*)(slice + b * 68);
        #pragma unroll
        for (int c = 0; c < 16; ++c) dst[c] = s4[c];
    }
    asm volatile("s_waitcnt lgkmcnt(0)" ::: "memory");

    float g[25];
    #pragma unroll
    for (int a = 0; a < 25; ++a) g[a] = 0.0f;
    #pragma unroll 1
    for (int ch = 0; ch < 4; ++ch) {
        float ow[16];
        const float4* op = (const float4*)(slice + bb * 68);
        ((float4*)ow)[0] = op[ch * 4 + 0];
        ((float4*)ow)[1] = op[ch * 4 + 1];
        ((float4*)ow)[2] = op[ch * 4 + 2];
        ((float4*)ow)[3] = op[ch * 4 + 3];
        #pragma unroll
        for (int a = 0; a < 25; ++a) {
            float rr[16];
            const float4* rp = (const float4*)(slice + a * 68);
            ((float4*)rr)[0] = rp[ch * 4 + 0];
            ((float4*)rr)[1] = rp[ch * 4 + 1];
            ((float4*)rr)[2] = rp[ch * 4 + 2];
            ((float4*)rr)[3] = rp[ch * 4 + 3];
            float s = 0.0f;
            #pragma unroll
            for (int d4 = 0; d4 < 16; ++d4) s += ow[d4] * rr[d4];
            g[a] += s;
        }
    }

    {
        float rs_own = 0.0f;
        #pragma unroll
        for (int a = 0; a < 25; ++a) rs_own += g[a];
        float grand = 0.0f;
        float rsA[25];
        #pragma unroll
        for (int a = 0; a < 25; ++a) {
            rsA[a] = __shfl(rs_own, half * 32 + a);
            grand += rsA[a];
        }
        const float c1 = 1.0f / 25.0f, c2 = 1.0f / 625.0f;
        #pragma unroll
        for (int a = 0; a < 25; ++a)
            g[a] = g[a] - rsA[a] * c1 - rs_own * c1 + grand * c2;
    }

    #pragma unroll 1
    for (int rd = 0; rd < ROUNDS; ++rd) {
        float ss = 0.0f;
        #pragma unroll
        for (int r2 = 0; r2 < 25; ++r2) ss += g[r2] * g[r2];
        ss = act ? ss : 0.0f;
        #pragma unroll
        for (int off = 1; off < 32; off <<= 1) ss += __shfl_xor(ss, off);
        float inv = 1.0f / ss;
        if (act) {
            float4* gw = (float4*)(slice + b * 28);
            gw[0] = make_float4(g[0], g[1], g[2], g[3]);
            gw[1] = make_float4(g[4], g[5], g[6], g[7]);
            gw[2] = make_float4(g[8], g[9], g[10], g[11]);
            gw[3] = make_float4(g[12], g[13], g[14], g[15]);
            gw[4] = make_float4(g[16], g[17], g[18], g[19]);
            gw[5] = make_float4(g[20], g[21], g[22], g[23]);
            gw[6] = make_float4(g[24], 0.0f, 0.0f, 0.0f);
        }
        asm volatile("s_waitcnt lgkmcnt(0)" ::: "memory");
        float ng[25];
        #pragma unroll
        for (int r2 = 0; r2 < 25; ++r2) ng[r2] = 0.0f;
        #pragma unroll
        for (int c = 0; c < 25; ++c) {
            float cc2[28];
            const float4* gr = (const float4*)(slice + c * 28);
            ((float4*)cc2)[0] = gr[0];
            ((float4*)cc2)[1] = gr[1];
            ((float4*)cc2)[2] = gr[2];
            ((float4*)cc2)[3] = gr[3];
            ((float4*)cc2)[4] = gr[4];
            ((float4*)cc2)[5] = gr[5];
            ((float4*)cc2)[6] = gr[6];
            float m2 = g[c];
            #pragma unroll
            for (int r2 = 0; r2 < 25; ++r2) ng[r2] += cc2[r2] * m2;
        }
        #pragma unroll
        for (int r2 = 0; r2 < 25; ++r2) g[r2] = ng[r2] * inv;
    }

    if (act) {
        float4* gw = (float4*)(slice + b * 28);
        gw[0] = make_float4(g[0], g[1], g[2], g[3]);
        gw[1] = make_float4(g[4], g[5], g[6], g[7]);
        gw[2] = make_float4(g[8], g[9], g[10], g[11]);
        gw[3] = make_float4(g[12], g[13], g[14], g[15]);
        gw[4] = make_float4(g[16], g[17], g[18], g[19]);
        gw[5] = make_float4(g[20], g[21], g[22], g[23]);
        gw[6] = make_float4(g[24], 0.0f, 0.0f, 0.0f);
    }
    asm volatile("s_waitcnt lgkmcnt(0)" ::: "memory");

    float dv = act ? slice[b * 28 + b] : -1.0f;
    int bi = b;
    #pragma unroll
    for (int off = 1; off < 32; off <<= 1) {
        float ov = __shfl_xor(dv, off);
        int oi = __shfl_xor(bi, off);
        bool take = (ov > dv) || (ov == dv && oi < bi);
        dv = take ? ov : dv;
        bi = take ? oi : bi;
    }
    int jz = __shfl(bi, 0);
    int jxm = __shfl(bi, 32);

    const float* slice0 = pool[wv * 2 + 0];
    const float* slice1 = pool[wv * 2 + 1];
    float wzArr[28], wxArr[28];
    {
        const float4* wz4 = (const float4*)(slice0 + jz * 28);
        const float4* wx4 = (const float4*)(slice1 + jxm * 28);
        #pragma unroll
        for (int q = 0; q < 7; ++q) {
            ((float4*)wzArr)[q] = wz4[q];
            ((float4*)wxArr)[q] = wx4[q];
        }
    }
    float szs = 0.0f, sxs = 0.0f;
    #pragma unroll
    for (int k = 0; k < 25; ++k) { szs += wzArr[k]; sxs += wxArr[k]; }
    float azc = szs * (1.0f / 25.0f), axc = sxs * (1.0f / 25.0f);

    float uz = 0.0f, ux = 0.0f;
    #pragma unroll
    for (int k = 0; k < 25; ++k) {
        int nbz = __shfl(nb, k);
        int nbx = __shfl(nb, 32 + k);
        uz += latent[nbz * 64 + lane] * (wzArr[k] - azc);
        ux += raw[nbx * 64 + lane] * (wxArr[k] - axc);
    }
    float aa = uz * uz, bbv = ux * ux, ccv = uz * ux;
    #pragma unroll
    for (int off = 1; off < 64; off <<= 1) {
        aa += __shfl_xor(aa, off);
        bbv += __shfl_xor(bbv, off);
        ccv += __shfl_xor(ccv, off);
    }
    if (lane == 0) {
        float dot2 = (ccv * ccv) / fmaxf(aa * bbv, 1e-30f);
        tsaV[i] = 2.0f - 2.0f * dot2;
    }
}

// ---------------- final: out = sum(reconP)/524288 + 0.1*mean(tsaV) ----------
__global__ __launch_bounds__(256) void tsa_final_kernel(const float* __restrict__ tsaV,
                                                        const float* __restrict__ reconP,
                                                        float* __restrict__ out) {
    const int t = threadIdx.x;
    float s = 0.0f;
    const float4* v4 = (const float4*)tsaV;
    for (int e = t; e < 2048; e += 256) {
        float4 v = v4[e];
        s += (v.x + v.y) + (v.z + v.w);
    }
    float r = 0.0f;
    if (t < 128) {
        float4 p = ((const float4*)reconP)[t];
        r = (p.x + p.y) + (p.z + p.w);
    }
    #pragma unroll
    for (int off = 1; off < 64; off <<= 1) {
        s += __shfl_xor(s, off);
        r += __shfl_xor(r, off);
    }
    __shared__ float ps[4], pr[4];
    if ((t & 63) == 0) { ps[t >> 6] = s; pr[t >> 6] = r; }
    __syncthreads();
    if (t == 0) {
        float tot = ps[0] + ps[1] + ps[2] + ps[3];
        float rec = pr[0] + pr[1] + pr[2] + pr[3];
        out[0] = rec * (1.0f / 524288.0f) + 0.1f * (tot * (1.0f / 8192.0f));
    }
}

extern "C" void kernel_launch(void* const* d_in, const int* in_sizes, int n_in,
                              void* d_out, int out_size, void* d_ws, size_t ws_size,
                              hipStream_t stream) {
    const float* outputs = (const float*)d_in[0];
    const float* targets = (const float*)d_in[1];
    const float* latent  = (const float*)d_in[2];
    const float* raw     = (const float*)d_in[3];

    float* ws = (float*)d_ws;
    // ws layout (floats):
    float* sq     = ws;                        // 8192
    float* rawT   = ws + 8192;                 // 524288
    int*   nbrs   = (int*)(ws + 532480);       // 204800 -> 737280
    float* reconP = ws + 737280;               // 512
    float* tsaV   = ws + 737792;               // 8192 -> 745984
    float* sel26V = ws + 745984;               // 8192*26 = 212992 -> 958976
    int*   sel26J = (int*)(ws + 958976);       // 212992 -> 1171968
    int*   cnt    = (int*)(ws + 1171968);      // 8192*12 = 98304 -> 1270272
    float* survV  = ws + 1270272;              // 8192*12*32 = 3145728 -> 4416000
    int*   survJ  = (int*)(ws + 4416000);      // 3145728 -> 7561728
    float* d2_0   = ws + 7561728;              // RB * 2048

    size_t availF = ws_size / 4;
    int RB = 8192;
    while (RB > 1024 && (size_t)7561728 + (size_t)RB * W0 > availF) RB >>= 1;

    tsa_prep_kernel<<<2688, 256, 0, stream>>>(raw, outputs, targets, sq, rawT, reconP);

    for (int rb = 0; rb < 8192; rb += RB) {
        dim3 g(W0 / 128, RB / 128);
        tsa_dist0_kernel<<<g, 256, 0, stream>>>(rawT, sq, d2_0, rb);
        tsa_sel0_kernel<<<RB / 4, 256, 0, stream>>>(d2_0, sel26V, sel26J, rb);
    }
    {
        dim3 g(NCH, 64);
        tsa_filter_kernel<<<g, 256, 0, stream>>>(rawT, sq, sel26V, sel26J, survV, survJ, cnt);
    }
    tsa_merge_kernel<<<2048, 256, 0, stream>>>(sel26V, sel26J, survV, survJ, cnt, nbrs);
    tsa_eigen_kernel<<<2048, 256, 0, stream>>>(nbrs, latent, raw, tsaV);
    tsa_final_kernel<<<1, 256, 0, stream>>>(tsaV, reconP, (float*)d_out);
}